// Round 14
// baseline (1319.658 us; speedup 1.0000x reference)
//
#include <hip/hip_runtime.h>
#include <hip/hip_bf16.h>
#include <stdint.h>

#define DIM    128
#define KMAX   32
#define LN_EPS 1e-5f
#define ATT_SCALE 0.17677669529663687f   // 32^-0.5
#define CAND   2048
#define KCH    512                       // knn_sel center chunk (divisible by 4)
#define WTOT   214400                    // 212992 weight f32 + 1408 param f32

typedef unsigned long long u64;
static __device__ __forceinline__ float bf2f(__hip_bfloat16 x) { return __bfloat162float(x); }

// ---- bit-exact replica of the np-fp32 distance pipeline (DO NOT TOUCH: passing) ----
static __device__ __forceinline__ float norm32(float x, float y, float z) {
    return __fadd_rn(__fadd_rn(__fmul_rn(x, x), __fmul_rn(y, y)), __fmul_rn(z, z));
}
static __device__ __forceinline__ float d2_32(float cx, float cy, float cz, float cw,
                                              float px, float py, float pz, float pw) {
    float dot = __fmaf_rn(cz, pz, __fmaf_rn(cy, py, __fmul_rn(cx, px)));
    return __fsub_rn(__fadd_rn(cw, pw), __fmul_rn(2.0f, dot));
}
static __device__ __forceinline__ float d2_to_dist(float d2) {
    d2 = fmaxf(d2, 0.0f);
    return (d2 > 0.0f) ? __fsqrt_rn(d2) : 0.0f;
}
static __device__ __forceinline__ float dist32(float cx, float cy, float cz, float cw,
                                               float px, float py, float pz, float pw) {
    return d2_to_dist(d2_32(cx, cy, cz, cw, px, py, pz, pw));
}

static __device__ __forceinline__ float ldf(const void* p, int f32, size_t i) {
    return f32 ? ((const float*)p)[i] : bf2f(((const __hip_bfloat16*)p)[i]);
}
static __device__ __forceinline__ int ldidx(const void* p, int i64, int m) {
    return i64 ? ((const int*)p)[2 * m] : ((const int*)p)[m];
}

struct Ptrs { const void* p[18]; int sz[18]; };

// ---------- probe: classify each input's dtype on-device (unchanged, passing) ----------
__global__ void probe_dtypes(Ptrs P, int* __restrict__ fl) {
    int j = threadIdx.x;
    if (j >= 18) return;
    const void* x = P.p[j];
    int sz = P.sz[j];
    int flag = 0;
    if (j == 17) {
        const int* ip = (const int*)x;
        int odd_zero = 1, even_nz = 0;
        for (int k = 0; k < 8 && 2 * k + 1 < sz * 2; ++k) {
            if (ip[2 * k + 1] != 0) odd_zero = 0;
            if (ip[2 * k] != 0) even_nz = 1;
        }
        flag = (odd_zero && even_nz) ? 1 : 0;
    } else {
        const __hip_bfloat16* hp = (const __hip_bfloat16*)x;
        int n = sz < 256 ? sz : 256;
        for (int i = 0; i < n; ++i) {
            float w = bf2f(hp[i]);
            if (w != w || fabsf(w) > 1000.0f) { flag = 1; break; }
        }
        if ((j == 7 || j == 9) && bf2f(hp[0]) == 0.0f) flag = 1;
    }
    fl[j] = flag;
}

// ---------- convert weights+params -> canonical fp32 (unchanged) ----------
__global__ __launch_bounds__(256) void conv_params(Ptrs P, const int* __restrict__ fl,
                                                   float* __restrict__ Wf) {
    int i = blockIdx.x * 256 + threadIdx.x;
    if (i >= WTOT) return;
    int j, off;
    if      (i < 16384)  { j = 2;  off = i; }
    else if (i < 32768)  { j = 3;  off = i - 16384; }
    else if (i < 49152)  { j = 4;  off = i - 32768; }
    else if (i < 65536)  { j = 5;  off = i - 49152; }
    else if (i < 131072) { j = 11; off = i - 65536; }
    else if (i < 196608) { j = 13; off = i - 131072; }
    else if (i < 212992) { j = 15; off = i - 196608; }
    else if (i < 213120) { j = 6;  off = i - 212992; }
    else if (i < 213248) { j = 7;  off = i - 213120; }
    else if (i < 213376) { j = 8;  off = i - 213248; }
    else if (i < 213504) { j = 9;  off = i - 213376; }
    else if (i < 213632) { j = 10; off = i - 213504; }
    else if (i < 214144) { j = 12; off = i - 213632; }
    else if (i < 214272) { j = 14; off = i - 214144; }
    else                 { j = 16; off = i - 214272; }
    Wf[i] = ldf(P.p[j], fl[j], off);
}

__global__ void prep_pts(const void* __restrict__ xyz, const int* __restrict__ fl,
                         float4* __restrict__ pnt4, int N) {
    int i = blockIdx.x * 256 + threadIdx.x;
    if (i < N) {
        int f = fl[0];
        float x = ldf(xyz, f, 3 * i + 0), y = ldf(xyz, f, 3 * i + 1), z = ldf(xyz, f, 3 * i + 2);
        pnt4[i] = make_float4(x, y, z, norm32(x, y, z));
    }
}

__global__ void prep_ctrs(const void* __restrict__ idxc, const int* __restrict__ fl,
                          const float4* __restrict__ pnt4, float4* __restrict__ cent4,
                          int M, int N) {
    int m = blockIdx.x * 256 + threadIdx.x;
    if (m < M) {
        int c = ldidx(idxc, fl[17], m);
        c = (c >= 0 && c < N) ? c : 0;
        cent4[m] = pnt4[c];
    }
}

// =================== kernel: ball query scan + top-32 select -> nbr_g (unchanged) ===================
__global__ __launch_bounds__(256) void ball_scan(
    const float4* __restrict__ pnt4,
    const float4* __restrict__ cent4,
    int N, int* __restrict__ nbr_g) {

    __shared__ u64 key[CAND];        // 16 KB
    __shared__ int s_cnt, s_ni[KMAX];

    int m = blockIdx.x, tid = threadIdx.x;
    float4 cc4 = cent4[m];

    if (tid == 0) s_cnt = 0;
    if (tid < KMAX) s_ni[tid] = -1;
    __syncthreads();

    for (int i = tid; i < N; i += 256) {
        float4 p = pnt4[i];
        float d2 = d2_32(cc4.x, cc4.y, cc4.z, cc4.w, p.x, p.y, p.z, p.w);
        if (d2 < 0.0901f) {
            float dist = d2_to_dist(d2);
            if (dist < 0.3f) {
                int pos = atomicAdd(&s_cnt, 1);
                if (pos < CAND)
                    key[pos] = ((u64)__float_as_uint(dist) << 32) | (unsigned)i;
            }
        }
    }
    __syncthreads();
    int cnt = min(s_cnt, CAND);

    for (int i = tid; i < cnt; i += 256) {
        u64 ki = key[i];
        int r = 0;
        for (int j = 0; j < cnt; ++j) r += (key[j] < ki) ? 1 : 0;
        if (r < KMAX) s_ni[r] = (int)(unsigned)(ki & 0xFFFFFFFFULL);
    }
    __syncthreads();
    if (tid < KMAX) nbr_g[m * KMAX + tid] = s_ni[tid];
}

// =================== kernel: attention + FFN -> cf (unchanged, passing) ===================
__global__ __launch_bounds__(256) void attn_ffn(
    const int* __restrict__ nbr_g,
    const void* __restrict__ feats,
    const void* __restrict__ idxc,
    const int* __restrict__ fl,
    const float* __restrict__ Wf,
    float* __restrict__ cf_out, int N) {

    const float* Wqf = Wf;
    const float* Wkf = Wf + 16384;
    const float* Wvf = Wf + 32768;
    const float* Wof = Wf + 49152;
    const float* W1f = Wf + 65536;
    const float* W2f = Wf + 131072;
    const float* Pf  = Wf + 212992;

    __shared__ __align__(16) float nft[DIM][33];
    __shared__ float s_kv[KMAX][130];
    __shared__ int   s_ni[KMAX];
    __shared__ __align__(16) float s_cf[DIM], s_q[DIM], s_attn[DIM], s_ao[DIM], s_x[DIM];
    __shared__ float s_tree[128], s_part[256];
    __shared__ float s_hmax[4], s_hsum[4];

    int m = blockIdx.x, tid = threadIdx.x;
    int f1 = fl[1];
    int c = ldidx(idxc, fl[17], m);
    c = (c >= 0 && c < N) ? c : 0;

    if (tid < KMAX) s_ni[tid] = nbr_g[m * KMAX + tid];
    if (tid < 128) s_cf[tid] = ldf(feats, f1, (size_t)c * DIM + tid);
    __syncthreads();
    for (int t = tid; t < KMAX * DIM; t += 256) {
        int kk = t >> 7, cc = t & 127;
        int idx = s_ni[kk];
        float v = (idx >= 0 && idx < N) ? ldf(feats, f1, (size_t)idx * DIM + cc) : 0.0f;
        nft[cc][kk] = v;
    }
    __syncthreads();

    if (tid < 128) {
        float acc = 0.0f;
#pragma unroll 4
        for (int i = 0; i < DIM; i += 4) {
            float4 a = *(const float4*)&s_cf[i];
            acc = fmaf(a.x, Wqf[(i + 0) * DIM + tid], acc);
            acc = fmaf(a.y, Wqf[(i + 1) * DIM + tid], acc);
            acc = fmaf(a.z, Wqf[(i + 2) * DIM + tid], acc);
            acc = fmaf(a.w, Wqf[(i + 3) * DIM + tid], acc);
        }
        s_q[tid] = acc;
    }

    int mat = tid >> 7, col = tid & 127;
    const float* Wm = mat ? Wvf : Wkf;
    float acc[KMAX];
#pragma unroll
    for (int kk = 0; kk < KMAX; ++kk) acc[kk] = 0.0f;
    for (int i = 0; i < DIM; ++i) {
        float w = Wm[i * DIM + col];
#pragma unroll
        for (int k4 = 0; k4 < 8; ++k4) {
            float4 n = *(const float4*)&nft[i][k4 * 4];
            acc[k4 * 4 + 0] = fmaf(n.x, w, acc[k4 * 4 + 0]);
            acc[k4 * 4 + 1] = fmaf(n.y, w, acc[k4 * 4 + 1]);
            acc[k4 * 4 + 2] = fmaf(n.z, w, acc[k4 * 4 + 2]);
            acc[k4 * 4 + 3] = fmaf(n.w, w, acc[k4 * 4 + 3]);
        }
    }
    if (mat == 0) {
#pragma unroll
        for (int kk = 0; kk < KMAX; ++kk) s_kv[kk][col] = acc[kk];
    }
    __syncthreads();

    if (tid < 128) {
        int h = tid >> 5, kk = tid & 31;
        float s = 0.0f;
#pragma unroll
        for (int d = 0; d < 32; ++d)
            s = fmaf(s_q[h * 32 + d], s_kv[kk][h * 32 + d], s);
        s *= ATT_SCALE;
        if (s_ni[kk] < 0) s = -1e9f;
        s_attn[tid] = s;
    }
    __syncthreads();
    if (tid < 4) {
        float mx = -3.4e38f;
        for (int kk = 0; kk < 32; ++kk) mx = fmaxf(mx, s_attn[tid * 32 + kk]);
        float sm = 0.0f;
        for (int kk = 0; kk < 32; ++kk) sm += expf(s_attn[tid * 32 + kk] - mx);
        s_hmax[tid] = mx;
        s_hsum[tid] = (sm > 0.0f) ? sm : 1.0f;
    }
    __syncthreads();
    if (tid < 128)
        s_attn[tid] = expf(s_attn[tid] - s_hmax[tid >> 5]) / s_hsum[tid >> 5];
    __syncthreads();

    if (mat == 1) {
#pragma unroll
        for (int kk = 0; kk < KMAX; ++kk) s_kv[kk][col] = acc[kk];
    }
    __syncthreads();

    if (tid < 128) {
        int h = tid >> 5, d = tid & 31;
        float o = 0.0f;
#pragma unroll
        for (int kk = 0; kk < KMAX; ++kk)
            o = fmaf(s_attn[h * 32 + kk], s_kv[kk][h * 32 + d], o);
        s_ao[d * 4 + h] = o;
    }
    __syncthreads();

    float upd = 0.0f;
    if (tid < 128) {
        upd = Pf[0 + tid];  // bo
#pragma unroll 4
        for (int i = 0; i < DIM; i += 4) {
            float4 a = *(const float4*)&s_ao[i];
            upd = fmaf(a.x, Wof[(i + 0) * DIM + tid], upd);
            upd = fmaf(a.y, Wof[(i + 1) * DIM + tid], upd);
            upd = fmaf(a.z, Wof[(i + 2) * DIM + tid], upd);
            upd = fmaf(a.w, Wof[(i + 3) * DIM + tid], upd);
        }
    }
    if (tid < 128) s_tree[tid] = upd;
    __syncthreads();
    for (int s = 64; s > 0; s >>= 1) { if (tid < s) s_tree[tid] += s_tree[tid + s]; __syncthreads(); }
    float mu = s_tree[0] * (1.0f / 128.0f);
    __syncthreads();
    float xc = upd - mu;
    if (tid < 128) s_tree[tid] = xc * xc;
    __syncthreads();
    for (int s = 64; s > 0; s >>= 1) { if (tid < s) s_tree[tid] += s_tree[tid + s]; __syncthreads(); }
    float var = s_tree[0] * (1.0f / 128.0f);
    __syncthreads();
    float cf1 = 0.0f;
    if (tid < 128) {
        float rs = 1.0f / sqrtf(var + LN_EPS);
        float ln1 = fmaf(xc * rs, Pf[128 + tid], Pf[256 + tid]);  // n1w, n1b
        cf1 = s_cf[tid] + ln1;
        s_x[tid] = cf1;
    }
    __syncthreads();

    float* s_h = (float*)&nft[0][0];
#pragma unroll
    for (int jj = 0; jj < 2; ++jj) {
        int j = jj * 256 + tid;
        float a = Pf[640 + j];  // b1
#pragma unroll 4
        for (int i = 0; i < DIM; i += 4) {
            float4 v = *(const float4*)&s_x[i];
            a = fmaf(v.x, W1f[(i + 0) * 512 + j], a);
            a = fmaf(v.y, W1f[(i + 1) * 512 + j], a);
            a = fmaf(v.z, W1f[(i + 2) * 512 + j], a);
            a = fmaf(v.w, W1f[(i + 3) * 512 + j], a);
        }
        s_h[j] = fmaxf(a, 0.0f);
    }
    __syncthreads();

    int half = tid >> 7;
    float f2 = (half == 0) ? Pf[1152 + col] : 0.0f;  // b2
    {
        int i0 = half * 256;
#pragma unroll 4
        for (int i = i0; i < i0 + 256; i += 4) {
            float4 v = *(const float4*)&s_h[i];
            f2 = fmaf(v.x, W2f[(i + 0) * DIM + col], f2);
            f2 = fmaf(v.y, W2f[(i + 1) * DIM + col], f2);
            f2 = fmaf(v.z, W2f[(i + 2) * DIM + col], f2);
            f2 = fmaf(v.w, W2f[(i + 3) * DIM + col], f2);
        }
    }
    s_part[tid] = f2;
    __syncthreads();
    float ffn = 0.0f;
    if (tid < 128) ffn = s_part[tid] + s_part[tid + 128];
    if (tid < 128) s_tree[tid] = ffn;
    __syncthreads();
    for (int s = 64; s > 0; s >>= 1) { if (tid < s) s_tree[tid] += s_tree[tid + s]; __syncthreads(); }
    mu = s_tree[0] * (1.0f / 128.0f);
    __syncthreads();
    xc = ffn - mu;
    if (tid < 128) s_tree[tid] = xc * xc;
    __syncthreads();
    for (int s = 64; s > 0; s >>= 1) { if (tid < s) s_tree[tid] += s_tree[tid + s]; __syncthreads(); }
    var = s_tree[0] * (1.0f / 128.0f);
    __syncthreads();
    if (tid < 128) {
        float rs2 = 1.0f / sqrtf(var + LN_EPS);
        float ln2 = fmaf(xc * rs2, Pf[384 + tid], Pf[512 + tid]);  // n2w, n2b
        cf_out[(size_t)m * DIM + tid] = cf1 + ln2;
    }
}

// =================== kernel: KNN top-8 + upsample -> up (staged in d_out) (unchanged) ===================
#define CSWAP(a, b) { if ((b) < (a)) { u64 t_ = (a); (a) = (b); (b) = t_; } }

__global__ __launch_bounds__(256) void knn_sel(
    const float4* __restrict__ pnt4,
    const float4* __restrict__ cent4,
    const float* __restrict__ cf,
    float* __restrict__ up,      // = d_out (staging)
    int N, int M) {

    __shared__ float4 s_cc[KCH];       // 8 KB
    __shared__ u64   s_keys[32][65];   // 16.6 KB
    __shared__ u64   s_sel[8][64];     // 4 KB
    __shared__ int   s_ki[8][64];      // 2 KB
    __shared__ float s_kw[8][64];      // 2 KB

    int tid = threadIdx.x;
    int lp = tid & 63, sc = tid >> 6;
    int base = blockIdx.x * 64;
    int p = base + lp;
    bool own = (p < N);

    float4 pp = make_float4(0.f, 0.f, 0.f, 0.f);
    if (own) pp = pnt4[p];

    u64 b0 = ~0ULL, b1 = ~0ULL, b2 = ~0ULL, b3 = ~0ULL,
        b4 = ~0ULL, b5 = ~0ULL, b6 = ~0ULL, b7 = ~0ULL;

    for (int c0 = 0; c0 < M; c0 += KCH) {
        int cn = min(KCH, M - c0);
        __syncthreads();
        for (int j = tid; j < cn; j += 256) s_cc[j] = cent4[c0 + j];
        __syncthreads();
        for (int j = sc; j < cn; j += 4) {
            float4 cc = s_cc[j];
            float dist = dist32(cc.x, cc.y, cc.z, cc.w, pp.x, pp.y, pp.z, pp.w);
            u64 key = ((u64)__float_as_uint(dist) << 32) | (unsigned)(c0 + j);
            if (key < b7) {
                b7 = key;
                CSWAP(b6, b7); CSWAP(b5, b6); CSWAP(b4, b5); CSWAP(b3, b4);
                CSWAP(b2, b3); CSWAP(b1, b2); CSWAP(b0, b1);
            }
        }
    }
    {
        u64 bb[8] = { b0, b1, b2, b3, b4, b5, b6, b7 };
#pragma unroll
        for (int r = 0; r < 8; ++r) s_keys[sc * 8 + r][lp] = bb[r];
    }
    __syncthreads();

    {
        u64 kq[8];
#pragma unroll
        for (int r = 0; r < 8; ++r) kq[r] = s_keys[sc * 8 + r][lp];
#pragma unroll
        for (int r = 0; r < 8; ++r) {
            u64 k = kq[r];
            int rank = 0;
            for (int j = 0; j < 32; ++j) rank += (s_keys[j][lp] < k) ? 1 : 0;
            if (rank < 8) s_sel[rank][lp] = k;
        }
    }
    __syncthreads();

    if (sc == 0) {
        if (own) {
            float wv[8], wsum = 0.0f;
#pragma unroll
            for (int k = 0; k < 8; ++k) {
                u64 key = s_sel[k][lp];
                float d = __uint_as_float((unsigned)(key >> 32));
                int ci = (int)(unsigned)(key & 0xFFFFFFFFULL);
                ci = (ci >= 0 && ci < M) ? ci : 0;
                float t = __fadd_rn(d, 1e-6f);
                wv[k] = 1.0f / __fmul_rn(t, t);
                wsum += wv[k];
                s_ki[k][lp] = ci;
            }
            float inv = 1.0f / wsum;
#pragma unroll
            for (int k = 0; k < 8; ++k) s_kw[k][lp] = wv[k] * inv;
        } else {
#pragma unroll
            for (int k = 0; k < 8; ++k) { s_ki[k][lp] = 0; s_kw[k][lp] = 0.0f; }
        }
    }
    __syncthreads();

    for (int t = tid; t < 64 * DIM; t += 256) {
        int r = t >> 7, cc = t & 127;
        int pg = base + r;
        if (pg < N) {
            float acc = 0.0f;
#pragma unroll
            for (int k = 0; k < 8; ++k)
                acc = fmaf(s_kw[k][r], cf[(size_t)s_ki[k][r] * DIM + cc], acc);
            up[(size_t)pg * DIM + cc] = acc;
        }
    }
}

// =================== kernel: out = feats + up + relu(up@Wp + bp), in-place on d_out ===================
// v2: 64 rows/block, acc[32]/thread, Wp chunk-staged in LDS -> zero global loads in hot loop.
// i-accumulation order 0..127 ascending (identical operands) -> bit-identical output.
__global__ __launch_bounds__(256) void wp_out(
    float* __restrict__ io,
    const void* __restrict__ feats,
    const int* __restrict__ fl,
    const float* __restrict__ Wf,
    int N) {

    const float* Wpf = Wf + 196608;
    const float* bpf = Wf + 212992 + 1280;

    __shared__ float s_t[DIM][65];      // transposed up tile [feat][row], 33.3 KB
    __shared__ float s_wp[32][DIM];     // Wp chunk, 16 KB

    int tid = threadIdx.x;
    int base = blockIdx.x * 64;
    int f1 = fl[1];
    int col = tid & 127, grp = tid >> 7;

    // stage-transpose 64 rows of up
    for (int t = tid; t < 64 * DIM; t += 256) {
        int r = t >> 7, cc = t & 127;
        int row = base + r;
        float v = (row < N) ? io[(size_t)row * DIM + cc] : 0.0f;
        s_t[cc][r] = v;
    }

    float acc[32];
#pragma unroll
    for (int r = 0; r < 32; ++r) acc[r] = 0.0f;

    for (int i0 = 0; i0 < DIM; i0 += 32) {
        __syncthreads();   // 1st iter: s_t staging complete; later: prev chunk compute done
        for (int t = tid; t < 32 * DIM; t += 256) {
            int ii = t >> 7, cc = t & 127;
            s_wp[ii][cc] = Wpf[(size_t)(i0 + ii) * DIM + cc];
        }
        __syncthreads();
#pragma unroll 2
        for (int ii = 0; ii < 32; ++ii) {
            float w = s_wp[ii][col];
            const float* tr = &s_t[i0 + ii][grp * 32];
#pragma unroll
            for (int r4 = 0; r4 < 8; ++r4) {
                float4 uv = *(const float4*)(tr + r4 * 4);
                acc[r4 * 4 + 0] = fmaf(uv.x, w, acc[r4 * 4 + 0]);
                acc[r4 * 4 + 1] = fmaf(uv.y, w, acc[r4 * 4 + 1]);
                acc[r4 * 4 + 2] = fmaf(uv.z, w, acc[r4 * 4 + 2]);
                acc[r4 * 4 + 3] = fmaf(uv.w, w, acc[r4 * 4 + 3]);
            }
        }
    }

    float bp = bpf[col];
#pragma unroll
    for (int r = 0; r < 32; ++r) {
        int row = base + grp * 32 + r;
        if (row < N) {
            float upv = s_t[col][grp * 32 + r];
            float o = ldf(feats, f1, (size_t)row * DIM + col) + upv + fmaxf(bp + acc[r], 0.0f);
            io[(size_t)row * DIM + col] = o;
        }
    }
}

extern "C" void kernel_launch(void* const* d_in, const int* in_sizes, int n_in,
                              void* d_out, int out_size, void* d_ws, size_t ws_size,
                              hipStream_t stream) {
    int N = in_sizes[0] / 3;
    int M = in_sizes[17];

    Ptrs P;
    for (int j = 0; j < 18; ++j) { P.p[j] = d_in[j]; P.sz[j] = in_sizes[j]; }

    size_t off = 0;
    auto alloc = [&](size_t bytes) -> void* {
        off = (off + 255) & ~(size_t)255;
        void* p = (void*)((char*)d_ws + off);
        off += bytes;
        return p;
    };
    int*    fl    = (int*)alloc(32 * 4);
    float*  Wf    = (float*)alloc((size_t)WTOT * 4);          // 858 KB
    float4* pnt4  = (float4*)alloc((size_t)N * 16);           // 800 KB
    float4* cent4 = (float4*)alloc((size_t)M * 16);           //  40 KB
    float*  cfbuf = (float*)alloc((size_t)M * DIM * 4);       // 1.28 MB
    int*    nbr   = (int*)alloc((size_t)M * KMAX * 4);        // 320 KB (total ~3.3 MB)

    probe_dtypes<<<1, 32, 0, stream>>>(P, fl);
    conv_params<<<(WTOT + 255) / 256, 256, 0, stream>>>(P, fl, Wf);
    prep_pts<<<(N + 255) / 256, 256, 0, stream>>>(d_in[0], fl, pnt4, N);
    prep_ctrs<<<(M + 255) / 256, 256, 0, stream>>>(d_in[17], fl, pnt4, cent4, M, N);
    ball_scan<<<M, 256, 0, stream>>>(pnt4, cent4, N, nbr);
    attn_ffn<<<M, 256, 0, stream>>>(nbr, d_in[1], d_in[17], fl, Wf, cfbuf, N);
    knn_sel<<<(N + 63) / 64, 256, 0, stream>>>(pnt4, cent4, cfbuf, (float*)d_out, N, M);
    wp_out<<<(N + 31) / 32, 256, 0, stream>>>((float*)d_out, d_in[1], fl, Wf, N);
}

// Round 15
// 1063.630 us; speedup vs baseline: 1.2407x; 1.2407x over previous
//
#include <hip/hip_runtime.h>
#include <hip/hip_bf16.h>
#include <stdint.h>

#define DIM    128
#define KMAX   32
#define LN_EPS 1e-5f
#define ATT_SCALE 0.17677669529663687f   // 32^-0.5
#define CAND   2048
#define KCH    512                       // knn center chunk (divisible by 4)
#define WTOT   214400                    // 212992 weight f32 + 1408 param f32

typedef unsigned long long u64;
static __device__ __forceinline__ float bf2f(__hip_bfloat16 x) { return __bfloat162float(x); }

// ---- bit-exact replica of the np-fp32 distance pipeline (DO NOT TOUCH: passing) ----
static __device__ __forceinline__ float norm32(float x, float y, float z) {
    return __fadd_rn(__fadd_rn(__fmul_rn(x, x), __fmul_rn(y, y)), __fmul_rn(z, z));
}
static __device__ __forceinline__ float d2_32(float cx, float cy, float cz, float cw,
                                              float px, float py, float pz, float pw) {
    float dot = __fmaf_rn(cz, pz, __fmaf_rn(cy, py, __fmul_rn(cx, px)));
    return __fsub_rn(__fadd_rn(cw, pw), __fmul_rn(2.0f, dot));
}
static __device__ __forceinline__ float d2_to_dist(float d2) {
    d2 = fmaxf(d2, 0.0f);
    return (d2 > 0.0f) ? __fsqrt_rn(d2) : 0.0f;
}
static __device__ __forceinline__ float dist32(float cx, float cy, float cz, float cw,
                                               float px, float py, float pz, float pw) {
    return d2_to_dist(d2_32(cx, cy, cz, cw, px, py, pz, pw));
}

static __device__ __forceinline__ float ldf(const void* p, int f32, size_t i) {
    return f32 ? ((const float*)p)[i] : bf2f(((const __hip_bfloat16*)p)[i]);
}
static __device__ __forceinline__ int ldidx(const void* p, int i64, int m) {
    return i64 ? ((const int*)p)[2 * m] : ((const int*)p)[m];
}

struct Ptrs { const void* p[18]; int sz[18]; };

// ---------- probe: classify each input's dtype on-device (unchanged, passing) ----------
__global__ void probe_dtypes(Ptrs P, int* __restrict__ fl) {
    int j = threadIdx.x;
    if (j >= 18) return;
    const void* x = P.p[j];
    int sz = P.sz[j];
    int flag = 0;
    if (j == 17) {
        const int* ip = (const int*)x;
        int odd_zero = 1, even_nz = 0;
        for (int k = 0; k < 8 && 2 * k + 1 < sz * 2; ++k) {
            if (ip[2 * k + 1] != 0) odd_zero = 0;
            if (ip[2 * k] != 0) even_nz = 1;
        }
        flag = (odd_zero && even_nz) ? 1 : 0;
    } else {
        const __hip_bfloat16* hp = (const __hip_bfloat16*)x;
        int n = sz < 256 ? sz : 256;
        for (int i = 0; i < n; ++i) {
            float w = bf2f(hp[i]);
            if (w != w || fabsf(w) > 1000.0f) { flag = 1; break; }
        }
        if ((j == 7 || j == 9) && bf2f(hp[0]) == 0.0f) flag = 1;
    }
    fl[j] = flag;
}

// ---------- convert weights+params -> canonical fp32 (unchanged) ----------
__global__ __launch_bounds__(256) void conv_params(Ptrs P, const int* __restrict__ fl,
                                                   float* __restrict__ Wf) {
    int i = blockIdx.x * 256 + threadIdx.x;
    if (i >= WTOT) return;
    int j, off;
    if      (i < 16384)  { j = 2;  off = i; }
    else if (i < 32768)  { j = 3;  off = i - 16384; }
    else if (i < 49152)  { j = 4;  off = i - 32768; }
    else if (i < 65536)  { j = 5;  off = i - 49152; }
    else if (i < 131072) { j = 11; off = i - 65536; }
    else if (i < 196608) { j = 13; off = i - 131072; }
    else if (i < 212992) { j = 15; off = i - 196608; }
    else if (i < 213120) { j = 6;  off = i - 212992; }
    else if (i < 213248) { j = 7;  off = i - 213120; }
    else if (i < 213376) { j = 8;  off = i - 213248; }
    else if (i < 213504) { j = 9;  off = i - 213376; }
    else if (i < 213632) { j = 10; off = i - 213504; }
    else if (i < 214144) { j = 12; off = i - 213632; }
    else if (i < 214272) { j = 14; off = i - 214144; }
    else                 { j = 16; off = i - 214272; }
    Wf[i] = ldf(P.p[j], fl[j], off);
}

__global__ void prep_pts(const void* __restrict__ xyz, const int* __restrict__ fl,
                         float4* __restrict__ pnt4, int N) {
    int i = blockIdx.x * 256 + threadIdx.x;
    if (i < N) {
        int f = fl[0];
        float x = ldf(xyz, f, 3 * i + 0), y = ldf(xyz, f, 3 * i + 1), z = ldf(xyz, f, 3 * i + 2);
        pnt4[i] = make_float4(x, y, z, norm32(x, y, z));
    }
}

__global__ void prep_ctrs(const void* __restrict__ idxc, const int* __restrict__ fl,
                          const float4* __restrict__ pnt4, float4* __restrict__ cent4,
                          int M, int N) {
    int m = blockIdx.x * 256 + threadIdx.x;
    if (m < M) {
        int c = ldidx(idxc, fl[17], m);
        c = (c >= 0 && c < N) ? c : 0;
        cent4[m] = pnt4[c];
    }
}

// =================== kernel: ball query scan + top-32 select -> nbr_g (unchanged) ===================
__global__ __launch_bounds__(256) void ball_scan(
    const float4* __restrict__ pnt4,
    const float4* __restrict__ cent4,
    int N, int* __restrict__ nbr_g) {

    __shared__ u64 key[CAND];        // 16 KB
    __shared__ int s_cnt, s_ni[KMAX];

    int m = blockIdx.x, tid = threadIdx.x;
    float4 cc4 = cent4[m];

    if (tid == 0) s_cnt = 0;
    if (tid < KMAX) s_ni[tid] = -1;
    __syncthreads();

    for (int i = tid; i < N; i += 256) {
        float4 p = pnt4[i];
        float d2 = d2_32(cc4.x, cc4.y, cc4.z, cc4.w, p.x, p.y, p.z, p.w);
        if (d2 < 0.0901f) {
            float dist = d2_to_dist(d2);
            if (dist < 0.3f) {
                int pos = atomicAdd(&s_cnt, 1);
                if (pos < CAND)
                    key[pos] = ((u64)__float_as_uint(dist) << 32) | (unsigned)i;
            }
        }
    }
    __syncthreads();
    int cnt = min(s_cnt, CAND);

    for (int i = tid; i < cnt; i += 256) {
        u64 ki = key[i];
        int r = 0;
        for (int j = 0; j < cnt; ++j) r += (key[j] < ki) ? 1 : 0;
        if (r < KMAX) s_ni[r] = (int)(unsigned)(ki & 0xFFFFFFFFULL);
    }
    __syncthreads();
    if (tid < KMAX) nbr_g[m * KMAX + tid] = s_ni[tid];
}

// =================== kernel: attention + FFN -> cf (unchanged, passing) ===================
__global__ __launch_bounds__(256) void attn_ffn(
    const int* __restrict__ nbr_g,
    const void* __restrict__ feats,
    const void* __restrict__ idxc,
    const int* __restrict__ fl,
    const float* __restrict__ Wf,
    float* __restrict__ cf_out, int N) {

    const float* Wqf = Wf;
    const float* Wkf = Wf + 16384;
    const float* Wvf = Wf + 32768;
    const float* Wof = Wf + 49152;
    const float* W1f = Wf + 65536;
    const float* W2f = Wf + 131072;
    const float* Pf  = Wf + 212992;

    __shared__ __align__(16) float nft[DIM][33];
    __shared__ float s_kv[KMAX][130];
    __shared__ int   s_ni[KMAX];
    __shared__ __align__(16) float s_cf[DIM], s_q[DIM], s_attn[DIM], s_ao[DIM], s_x[DIM];
    __shared__ float s_tree[128], s_part[256];
    __shared__ float s_hmax[4], s_hsum[4];

    int m = blockIdx.x, tid = threadIdx.x;
    int f1 = fl[1];
    int c = ldidx(idxc, fl[17], m);
    c = (c >= 0 && c < N) ? c : 0;

    if (tid < KMAX) s_ni[tid] = nbr_g[m * KMAX + tid];
    if (tid < 128) s_cf[tid] = ldf(feats, f1, (size_t)c * DIM + tid);
    __syncthreads();
    for (int t = tid; t < KMAX * DIM; t += 256) {
        int kk = t >> 7, cc = t & 127;
        int idx = s_ni[kk];
        float v = (idx >= 0 && idx < N) ? ldf(feats, f1, (size_t)idx * DIM + cc) : 0.0f;
        nft[cc][kk] = v;
    }
    __syncthreads();

    if (tid < 128) {
        float acc = 0.0f;
#pragma unroll 4
        for (int i = 0; i < DIM; i += 4) {
            float4 a = *(const float4*)&s_cf[i];
            acc = fmaf(a.x, Wqf[(i + 0) * DIM + tid], acc);
            acc = fmaf(a.y, Wqf[(i + 1) * DIM + tid], acc);
            acc = fmaf(a.z, Wqf[(i + 2) * DIM + tid], acc);
            acc = fmaf(a.w, Wqf[(i + 3) * DIM + tid], acc);
        }
        s_q[tid] = acc;
    }

    int mat = tid >> 7, col = tid & 127;
    const float* Wm = mat ? Wvf : Wkf;
    float acc[KMAX];
#pragma unroll
    for (int kk = 0; kk < KMAX; ++kk) acc[kk] = 0.0f;
    for (int i = 0; i < DIM; ++i) {
        float w = Wm[i * DIM + col];
#pragma unroll
        for (int k4 = 0; k4 < 8; ++k4) {
            float4 n = *(const float4*)&nft[i][k4 * 4];
            acc[k4 * 4 + 0] = fmaf(n.x, w, acc[k4 * 4 + 0]);
            acc[k4 * 4 + 1] = fmaf(n.y, w, acc[k4 * 4 + 1]);
            acc[k4 * 4 + 2] = fmaf(n.z, w, acc[k4 * 4 + 2]);
            acc[k4 * 4 + 3] = fmaf(n.w, w, acc[k4 * 4 + 3]);
        }
    }
    if (mat == 0) {
#pragma unroll
        for (int kk = 0; kk < KMAX; ++kk) s_kv[kk][col] = acc[kk];
    }
    __syncthreads();

    if (tid < 128) {
        int h = tid >> 5, kk = tid & 31;
        float s = 0.0f;
#pragma unroll
        for (int d = 0; d < 32; ++d)
            s = fmaf(s_q[h * 32 + d], s_kv[kk][h * 32 + d], s);
        s *= ATT_SCALE;
        if (s_ni[kk] < 0) s = -1e9f;
        s_attn[tid] = s;
    }
    __syncthreads();
    if (tid < 4) {
        float mx = -3.4e38f;
        for (int kk = 0; kk < 32; ++kk) mx = fmaxf(mx, s_attn[tid * 32 + kk]);
        float sm = 0.0f;
        for (int kk = 0; kk < 32; ++kk) sm += expf(s_attn[tid * 32 + kk] - mx);
        s_hmax[tid] = mx;
        s_hsum[tid] = (sm > 0.0f) ? sm : 1.0f;
    }
    __syncthreads();
    if (tid < 128)
        s_attn[tid] = expf(s_attn[tid] - s_hmax[tid >> 5]) / s_hsum[tid >> 5];
    __syncthreads();

    if (mat == 1) {
#pragma unroll
        for (int kk = 0; kk < KMAX; ++kk) s_kv[kk][col] = acc[kk];
    }
    __syncthreads();

    if (tid < 128) {
        int h = tid >> 5, d = tid & 31;
        float o = 0.0f;
#pragma unroll
        for (int kk = 0; kk < KMAX; ++kk)
            o = fmaf(s_attn[h * 32 + kk], s_kv[kk][h * 32 + d], o);
        s_ao[d * 4 + h] = o;
    }
    __syncthreads();

    float upd = 0.0f;
    if (tid < 128) {
        upd = Pf[0 + tid];  // bo
#pragma unroll 4
        for (int i = 0; i < DIM; i += 4) {
            float4 a = *(const float4*)&s_ao[i];
            upd = fmaf(a.x, Wof[(i + 0) * DIM + tid], upd);
            upd = fmaf(a.y, Wof[(i + 1) * DIM + tid], upd);
            upd = fmaf(a.z, Wof[(i + 2) * DIM + tid], upd);
            upd = fmaf(a.w, Wof[(i + 3) * DIM + tid], upd);
        }
    }
    if (tid < 128) s_tree[tid] = upd;
    __syncthreads();
    for (int s = 64; s > 0; s >>= 1) { if (tid < s) s_tree[tid] += s_tree[tid + s]; __syncthreads(); }
    float mu = s_tree[0] * (1.0f / 128.0f);
    __syncthreads();
    float xc = upd - mu;
    if (tid < 128) s_tree[tid] = xc * xc;
    __syncthreads();
    for (int s = 64; s > 0; s >>= 1) { if (tid < s) s_tree[tid] += s_tree[tid + s]; __syncthreads(); }
    float var = s_tree[0] * (1.0f / 128.0f);
    __syncthreads();
    float cf1 = 0.0f;
    if (tid < 128) {
        float rs = 1.0f / sqrtf(var + LN_EPS);
        float ln1 = fmaf(xc * rs, Pf[128 + tid], Pf[256 + tid]);  // n1w, n1b
        cf1 = s_cf[tid] + ln1;
        s_x[tid] = cf1;
    }
    __syncthreads();

    float* s_h = (float*)&nft[0][0];
#pragma unroll
    for (int jj = 0; jj < 2; ++jj) {
        int j = jj * 256 + tid;
        float a = Pf[640 + j];  // b1
#pragma unroll 4
        for (int i = 0; i < DIM; i += 4) {
            float4 v = *(const float4*)&s_x[i];
            a = fmaf(v.x, W1f[(i + 0) * 512 + j], a);
            a = fmaf(v.y, W1f[(i + 1) * 512 + j], a);
            a = fmaf(v.z, W1f[(i + 2) * 512 + j], a);
            a = fmaf(v.w, W1f[(i + 3) * 512 + j], a);
        }
        s_h[j] = fmaxf(a, 0.0f);
    }
    __syncthreads();

    int half = tid >> 7;
    float f2 = (half == 0) ? Pf[1152 + col] : 0.0f;  // b2
    {
        int i0 = half * 256;
#pragma unroll 4
        for (int i = i0; i < i0 + 256; i += 4) {
            float4 v = *(const float4*)&s_h[i];
            f2 = fmaf(v.x, W2f[(i + 0) * DIM + col], f2);
            f2 = fmaf(v.y, W2f[(i + 1) * DIM + col], f2);
            f2 = fmaf(v.z, W2f[(i + 2) * DIM + col], f2);
            f2 = fmaf(v.w, W2f[(i + 3) * DIM + col], f2);
        }
    }
    s_part[tid] = f2;
    __syncthreads();
    float ffn = 0.0f;
    if (tid < 128) ffn = s_part[tid] + s_part[tid + 128];
    if (tid < 128) s_tree[tid] = ffn;
    __syncthreads();
    for (int s = 64; s > 0; s >>= 1) { if (tid < s) s_tree[tid] += s_tree[tid + s]; __syncthreads(); }
    mu = s_tree[0] * (1.0f / 128.0f);
    __syncthreads();
    xc = ffn - mu;
    if (tid < 128) s_tree[tid] = xc * xc;
    __syncthreads();
    for (int s = 64; s > 0; s >>= 1) { if (tid < s) s_tree[tid] += s_tree[tid + s]; __syncthreads(); }
    var = s_tree[0] * (1.0f / 128.0f);
    __syncthreads();
    if (tid < 128) {
        float rs2 = 1.0f / sqrtf(var + LN_EPS);
        float ln2 = fmaf(xc * rs2, Pf[384 + tid], Pf[512 + tid]);  // n2w, n2b
        cf_out[(size_t)m * DIM + tid] = cf1 + ln2;
    }
}

// =================== fused kernel: KNN top-8 + upsample (LDS) + Wp GEMM + out ===================
// 64 points/block, grid (N+63)/64. up never touches global: upsample writes the transposed
// LDS tile s_t (union overlay on dead scan buffers), GEMM + output follow immediately.
// Selection, weight order, i-ascending accumulation identical -> bit-identical output.
#define CSWAP(a, b) { if ((b) < (a)) { u64 t_ = (a); (a) = (b); (b) = t_; } }

__global__ __launch_bounds__(256) void knn_wp(
    const float4* __restrict__ pnt4,
    const float4* __restrict__ cent4,
    const float* __restrict__ cf,
    const float* __restrict__ Wf,
    const void* __restrict__ feats,
    const int* __restrict__ fl,
    float* __restrict__ out, int N, int M) {

    const float* Wpf = Wf + 196608;
    const float* bpf = Wf + 212992 + 1280;

    __shared__ union UU {
        struct {
            float4 cc[KCH];          // 8 KB
            u64 keys[32][65];        // 16.6 KB
            u64 sel[8][64];          // 4 KB
        } a;
        float t[DIM][65];            // 33.3 KB (transposed up tile)
    } u;
    __shared__ int   s_ki[8][64];    // 2 KB
    __shared__ float s_kw[8][64];    // 2 KB
    __shared__ float s_wp[32][DIM];  // 16 KB  (total ~53.5 KB -> 3 blocks/CU)

    int tid = threadIdx.x;
    int lp = tid & 63, sc = tid >> 6;
    int base = blockIdx.x * 64;
    int p = base + lp;
    bool own = (p < N);
    int f1 = fl[1];

    float4 pp = make_float4(0.f, 0.f, 0.f, 0.f);
    if (own) pp = pnt4[p];

    u64 b0 = ~0ULL, b1 = ~0ULL, b2 = ~0ULL, b3 = ~0ULL,
        b4 = ~0ULL, b5 = ~0ULL, b6 = ~0ULL, b7 = ~0ULL;

    // ---- phase A: scan (4 scanner-waves, LDS-staged centers) ----
    for (int c0 = 0; c0 < M; c0 += KCH) {
        int cn = min(KCH, M - c0);
        __syncthreads();
        for (int j = tid; j < cn; j += 256) u.a.cc[j] = cent4[c0 + j];
        __syncthreads();
        for (int j = sc; j < cn; j += 4) {
            float4 cc = u.a.cc[j];
            float dist = dist32(cc.x, cc.y, cc.z, cc.w, pp.x, pp.y, pp.z, pp.w);
            u64 key = ((u64)__float_as_uint(dist) << 32) | (unsigned)(c0 + j);
            if (key < b7) {
                b7 = key;
                CSWAP(b6, b7); CSWAP(b5, b6); CSWAP(b4, b5); CSWAP(b3, b4);
                CSWAP(b2, b3); CSWAP(b1, b2); CSWAP(b0, b1);
            }
        }
    }
    {
        u64 bb[8] = { b0, b1, b2, b3, b4, b5, b6, b7 };
#pragma unroll
        for (int r = 0; r < 8; ++r) u.a.keys[sc * 8 + r][lp] = bb[r];
    }
    __syncthreads();

    // ---- rank-merge (bit-identical global top-8, ascending) ----
    {
        u64 kq[8];
#pragma unroll
        for (int r = 0; r < 8; ++r) kq[r] = u.a.keys[sc * 8 + r][lp];
#pragma unroll
        for (int r = 0; r < 8; ++r) {
            u64 k = kq[r];
            int rank = 0;
            for (int j = 0; j < 32; ++j) rank += (u.a.keys[j][lp] < k) ? 1 : 0;
            if (rank < 8) u.a.sel[rank][lp] = k;
        }
    }
    __syncthreads();

    // ---- weights (same ascending summation order) ----
    if (sc == 0) {
        if (own) {
            float wv[8], wsum = 0.0f;
#pragma unroll
            for (int k = 0; k < 8; ++k) {
                u64 key = u.a.sel[k][lp];
                float d = __uint_as_float((unsigned)(key >> 32));
                int ci = (int)(unsigned)(key & 0xFFFFFFFFULL);
                ci = (ci >= 0 && ci < M) ? ci : 0;
                float t = __fadd_rn(d, 1e-6f);
                wv[k] = 1.0f / __fmul_rn(t, t);
                wsum += wv[k];
                s_ki[k][lp] = ci;
            }
            float inv = 1.0f / wsum;
#pragma unroll
            for (int k = 0; k < 8; ++k) s_kw[k][lp] = wv[k] * inv;
        } else {
#pragma unroll
            for (int k = 0; k < 8; ++k) { s_ki[k][lp] = 0; s_kw[k][lp] = 0.0f; }
        }
    }
    __syncthreads();   // weights done; u.a dead from here -> u.t may be written

    // ---- phase B: upsample into transposed LDS tile (no global round-trip) ----
    for (int t = tid; t < 64 * DIM; t += 256) {
        int r = t >> 7, cc = t & 127;
        float acc = 0.0f;
#pragma unroll
        for (int k = 0; k < 8; ++k)
            acc = fmaf(s_kw[k][r], cf[(size_t)s_ki[k][r] * DIM + cc], acc);
        u.t[cc][r] = acc;
    }

    // ---- phase C: GEMM acc[32] per thread; Wp chunk-staged via float4 ----
    int col = tid & 127, grp = tid >> 7;
    float acc[32];
#pragma unroll
    for (int r = 0; r < 32; ++r) acc[r] = 0.0f;

    for (int i0 = 0; i0 < DIM; i0 += 32) {
        __syncthreads();   // 1st iter: phase-B writes visible; later: prev chunk consumed
        for (int t = tid; t < 32 * DIM / 4; t += 256) {   // 1024 float4, 4/thread
            int ii = (t * 4) >> 7, cc = (t * 4) & 127;
            *(float4*)&s_wp[ii][cc] = *(const float4*)&Wpf[(size_t)(i0 + ii) * DIM + cc];
        }
        __syncthreads();
#pragma unroll 2
        for (int ii = 0; ii < 32; ++ii) {
            float w = s_wp[ii][col];
            const float* tr = &u.t[i0 + ii][grp * 32];
#pragma unroll
            for (int r4 = 0; r4 < 8; ++r4) {
                float4 uv = *(const float4*)(tr + r4 * 4);
                acc[r4 * 4 + 0] = fmaf(uv.x, w, acc[r4 * 4 + 0]);
                acc[r4 * 4 + 1] = fmaf(uv.y, w, acc[r4 * 4 + 1]);
                acc[r4 * 4 + 2] = fmaf(uv.z, w, acc[r4 * 4 + 2]);
                acc[r4 * 4 + 3] = fmaf(uv.w, w, acc[r4 * 4 + 3]);
            }
        }
    }

    // ---- phase D: out = feats + up + relu(bp + acc), coalesced per row ----
    float bp = bpf[col];
#pragma unroll
    for (int r = 0; r < 32; ++r) {
        int row = base + grp * 32 + r;
        if (row < N) {
            float upv = u.t[col][grp * 32 + r];
            float o = ldf(feats, f1, (size_t)row * DIM + col) + upv + fmaxf(bp + acc[r], 0.0f);
            out[(size_t)row * DIM + col] = o;
        }
    }
}

extern "C" void kernel_launch(void* const* d_in, const int* in_sizes, int n_in,
                              void* d_out, int out_size, void* d_ws, size_t ws_size,
                              hipStream_t stream) {
    int N = in_sizes[0] / 3;
    int M = in_sizes[17];

    Ptrs P;
    for (int j = 0; j < 18; ++j) { P.p[j] = d_in[j]; P.sz[j] = in_sizes[j]; }

    size_t off = 0;
    auto alloc = [&](size_t bytes) -> void* {
        off = (off + 255) & ~(size_t)255;
        void* p = (void*)((char*)d_ws + off);
        off += bytes;
        return p;
    };
    int*    fl    = (int*)alloc(32 * 4);
    float*  Wf    = (float*)alloc((size_t)WTOT * 4);          // 858 KB
    float4* pnt4  = (float4*)alloc((size_t)N * 16);           // 800 KB
    float4* cent4 = (float4*)alloc((size_t)M * 16);           //  40 KB
    float*  cfbuf = (float*)alloc((size_t)M * DIM * 4);       // 1.28 MB
    int*    nbr   = (int*)alloc((size_t)M * KMAX * 4);        // 320 KB (total ~3.3 MB)

    probe_dtypes<<<1, 32, 0, stream>>>(P, fl);
    conv_params<<<(WTOT + 255) / 256, 256, 0, stream>>>(P, fl, Wf);
    prep_pts<<<(N + 255) / 256, 256, 0, stream>>>(d_in[0], fl, pnt4, N);
    prep_ctrs<<<(M + 255) / 256, 256, 0, stream>>>(d_in[17], fl, pnt4, cent4, M, N);
    ball_scan<<<M, 256, 0, stream>>>(pnt4, cent4, N, nbr);
    attn_ffn<<<M, 256, 0, stream>>>(nbr, d_in[1], d_in[17], fl, Wf, cfbuf, N);
    knn_wp<<<(N + 63) / 64, 256, 0, stream>>>(pnt4, cent4, cfbuf, Wf, d_in[1], fl,
                                              (float*)d_out, N, M);
}

// Round 16
// 683.475 us; speedup vs baseline: 1.9308x; 1.5562x over previous
//
#include <hip/hip_runtime.h>
#include <hip/hip_bf16.h>
#include <stdint.h>

#define DIM    128
#define KMAX   32
#define LN_EPS 1e-5f
#define ATT_SCALE 0.17677669529663687f   // 32^-0.5
#define CAND   2048
#define WTOT   214400                    // 212992 weight f32 + 1408 param f32

typedef unsigned long long u64;
static __device__ __forceinline__ float bf2f(__hip_bfloat16 x) { return __bfloat162float(x); }

// ---- bit-exact replica of the np-fp32 distance pipeline (DO NOT TOUCH: passing) ----
static __device__ __forceinline__ float norm32(float x, float y, float z) {
    return __fadd_rn(__fadd_rn(__fmul_rn(x, x), __fmul_rn(y, y)), __fmul_rn(z, z));
}
static __device__ __forceinline__ float d2_32(float cx, float cy, float cz, float cw,
                                              float px, float py, float pz, float pw) {
    float dot = __fmaf_rn(cz, pz, __fmaf_rn(cy, py, __fmul_rn(cx, px)));
    return __fsub_rn(__fadd_rn(cw, pw), __fmul_rn(2.0f, dot));
}
static __device__ __forceinline__ float d2_to_dist(float d2) {
    d2 = fmaxf(d2, 0.0f);
    return (d2 > 0.0f) ? __fsqrt_rn(d2) : 0.0f;
}
static __device__ __forceinline__ float dist32(float cx, float cy, float cz, float cw,
                                               float px, float py, float pz, float pw) {
    return d2_to_dist(d2_32(cx, cy, cz, cw, px, py, pz, pw));
}

static __device__ __forceinline__ float ldf(const void* p, int f32, size_t i) {
    return f32 ? ((const float*)p)[i] : bf2f(((const __hip_bfloat16*)p)[i]);
}
static __device__ __forceinline__ int ldidx(const void* p, int i64, int m) {
    return i64 ? ((const int*)p)[2 * m] : ((const int*)p)[m];
}

struct Ptrs { const void* p[18]; int sz[18]; };

// ---------- probe: classify each input's dtype on-device (unchanged, passing) ----------
__global__ void probe_dtypes(Ptrs P, int* __restrict__ fl) {
    int j = threadIdx.x;
    if (j >= 18) return;
    const void* x = P.p[j];
    int sz = P.sz[j];
    int flag = 0;
    if (j == 17) {
        const int* ip = (const int*)x;
        int odd_zero = 1, even_nz = 0;
        for (int k = 0; k < 8 && 2 * k + 1 < sz * 2; ++k) {
            if (ip[2 * k + 1] != 0) odd_zero = 0;
            if (ip[2 * k] != 0) even_nz = 1;
        }
        flag = (odd_zero && even_nz) ? 1 : 0;
    } else {
        const __hip_bfloat16* hp = (const __hip_bfloat16*)x;
        int n = sz < 256 ? sz : 256;
        for (int i = 0; i < n; ++i) {
            float w = bf2f(hp[i]);
            if (w != w || fabsf(w) > 1000.0f) { flag = 1; break; }
        }
        if ((j == 7 || j == 9) && bf2f(hp[0]) == 0.0f) flag = 1;
    }
    fl[j] = flag;
}

// ---------- convert weights+params -> canonical fp32 (unchanged) ----------
__global__ __launch_bounds__(256) void conv_params(Ptrs P, const int* __restrict__ fl,
                                                   float* __restrict__ Wf) {
    int i = blockIdx.x * 256 + threadIdx.x;
    if (i >= WTOT) return;
    int j, off;
    if      (i < 16384)  { j = 2;  off = i; }
    else if (i < 32768)  { j = 3;  off = i - 16384; }
    else if (i < 49152)  { j = 4;  off = i - 32768; }
    else if (i < 65536)  { j = 5;  off = i - 49152; }
    else if (i < 131072) { j = 11; off = i - 65536; }
    else if (i < 196608) { j = 13; off = i - 131072; }
    else if (i < 212992) { j = 15; off = i - 196608; }
    else if (i < 213120) { j = 6;  off = i - 212992; }
    else if (i < 213248) { j = 7;  off = i - 213120; }
    else if (i < 213376) { j = 8;  off = i - 213248; }
    else if (i < 213504) { j = 9;  off = i - 213376; }
    else if (i < 213632) { j = 10; off = i - 213504; }
    else if (i < 214144) { j = 12; off = i - 213632; }
    else if (i < 214272) { j = 14; off = i - 214144; }
    else                 { j = 16; off = i - 214272; }
    Wf[i] = ldf(P.p[j], fl[j], off);
}

__global__ void prep_pts(const void* __restrict__ xyz, const int* __restrict__ fl,
                         float4* __restrict__ pnt4, int N) {
    int i = blockIdx.x * 256 + threadIdx.x;
    if (i < N) {
        int f = fl[0];
        float x = ldf(xyz, f, 3 * i + 0), y = ldf(xyz, f, 3 * i + 1), z = ldf(xyz, f, 3 * i + 2);
        pnt4[i] = make_float4(x, y, z, norm32(x, y, z));
    }
}

__global__ void prep_ctrs(const void* __restrict__ idxc, const int* __restrict__ fl,
                          const float4* __restrict__ pnt4, float4* __restrict__ cent4,
                          int M, int N) {
    int m = blockIdx.x * 256 + threadIdx.x;
    if (m < M) {
        int c = ldidx(idxc, fl[17], m);
        c = (c >= 0 && c < N) ? c : 0;
        cent4[m] = pnt4[c];
    }
}

// =================== kernel: ball query scan + top-32 select -> nbr_g (unchanged) ===================
__global__ __launch_bounds__(256) void ball_scan(
    const float4* __restrict__ pnt4,
    const float4* __restrict__ cent4,
    int N, int* __restrict__ nbr_g) {

    __shared__ u64 key[CAND];        // 16 KB
    __shared__ int s_cnt, s_ni[KMAX];

    int m = blockIdx.x, tid = threadIdx.x;
    float4 cc4 = cent4[m];

    if (tid == 0) s_cnt = 0;
    if (tid < KMAX) s_ni[tid] = -1;
    __syncthreads();

    for (int i = tid; i < N; i += 256) {
        float4 p = pnt4[i];
        float d2 = d2_32(cc4.x, cc4.y, cc4.z, cc4.w, p.x, p.y, p.z, p.w);
        if (d2 < 0.0901f) {
            float dist = d2_to_dist(d2);
            if (dist < 0.3f) {
                int pos = atomicAdd(&s_cnt, 1);
                if (pos < CAND)
                    key[pos] = ((u64)__float_as_uint(dist) << 32) | (unsigned)i;
            }
        }
    }
    __syncthreads();
    int cnt = min(s_cnt, CAND);

    for (int i = tid; i < cnt; i += 256) {
        u64 ki = key[i];
        int r = 0;
        for (int j = 0; j < cnt; ++j) r += (key[j] < ki) ? 1 : 0;
        if (r < KMAX) s_ni[r] = (int)(unsigned)(ki & 0xFFFFFFFFULL);
    }
    __syncthreads();
    if (tid < KMAX) nbr_g[m * KMAX + tid] = s_ni[tid];
}

// =================== kernel: attention + FFN -> cf (unchanged, passing) ===================
__global__ __launch_bounds__(256) void attn_ffn(
    const int* __restrict__ nbr_g,
    const void* __restrict__ feats,
    const void* __restrict__ idxc,
    const int* __restrict__ fl,
    const float* __restrict__ Wf,
    float* __restrict__ cf_out, int N) {

    const float* Wqf = Wf;
    const float* Wkf = Wf + 16384;
    const float* Wvf = Wf + 32768;
    const float* Wof = Wf + 49152;
    const float* W1f = Wf + 65536;
    const float* W2f = Wf + 131072;
    const float* Pf  = Wf + 212992;

    __shared__ __align__(16) float nft[DIM][33];
    __shared__ float s_kv[KMAX][130];
    __shared__ int   s_ni[KMAX];
    __shared__ __align__(16) float s_cf[DIM], s_q[DIM], s_attn[DIM], s_ao[DIM], s_x[DIM];
    __shared__ float s_tree[128], s_part[256];
    __shared__ float s_hmax[4], s_hsum[4];

    int m = blockIdx.x, tid = threadIdx.x;
    int f1 = fl[1];
    int c = ldidx(idxc, fl[17], m);
    c = (c >= 0 && c < N) ? c : 0;

    if (tid < KMAX) s_ni[tid] = nbr_g[m * KMAX + tid];
    if (tid < 128) s_cf[tid] = ldf(feats, f1, (size_t)c * DIM + tid);
    __syncthreads();
    for (int t = tid; t < KMAX * DIM; t += 256) {
        int kk = t >> 7, cc = t & 127;
        int idx = s_ni[kk];
        float v = (idx >= 0 && idx < N) ? ldf(feats, f1, (size_t)idx * DIM + cc) : 0.0f;
        nft[cc][kk] = v;
    }
    __syncthreads();

    if (tid < 128) {
        float acc = 0.0f;
#pragma unroll 4
        for (int i = 0; i < DIM; i += 4) {
            float4 a = *(const float4*)&s_cf[i];
            acc = fmaf(a.x, Wqf[(i + 0) * DIM + tid], acc);
            acc = fmaf(a.y, Wqf[(i + 1) * DIM + tid], acc);
            acc = fmaf(a.z, Wqf[(i + 2) * DIM + tid], acc);
            acc = fmaf(a.w, Wqf[(i + 3) * DIM + tid], acc);
        }
        s_q[tid] = acc;
    }

    int mat = tid >> 7, col = tid & 127;
    const float* Wm = mat ? Wvf : Wkf;
    float acc[KMAX];
#pragma unroll
    for (int kk = 0; kk < KMAX; ++kk) acc[kk] = 0.0f;
    for (int i = 0; i < DIM; ++i) {
        float w = Wm[i * DIM + col];
#pragma unroll
        for (int k4 = 0; k4 < 8; ++k4) {
            float4 n = *(const float4*)&nft[i][k4 * 4];
            acc[k4 * 4 + 0] = fmaf(n.x, w, acc[k4 * 4 + 0]);
            acc[k4 * 4 + 1] = fmaf(n.y, w, acc[k4 * 4 + 1]);
            acc[k4 * 4 + 2] = fmaf(n.z, w, acc[k4 * 4 + 2]);
            acc[k4 * 4 + 3] = fmaf(n.w, w, acc[k4 * 4 + 3]);
        }
    }
    if (mat == 0) {
#pragma unroll
        for (int kk = 0; kk < KMAX; ++kk) s_kv[kk][col] = acc[kk];
    }
    __syncthreads();

    if (tid < 128) {
        int h = tid >> 5, kk = tid & 31;
        float s = 0.0f;
#pragma unroll
        for (int d = 0; d < 32; ++d)
            s = fmaf(s_q[h * 32 + d], s_kv[kk][h * 32 + d], s);
        s *= ATT_SCALE;
        if (s_ni[kk] < 0) s = -1e9f;
        s_attn[tid] = s;
    }
    __syncthreads();
    if (tid < 4) {
        float mx = -3.4e38f;
        for (int kk = 0; kk < 32; ++kk) mx = fmaxf(mx, s_attn[tid * 32 + kk]);
        float sm = 0.0f;
        for (int kk = 0; kk < 32; ++kk) sm += expf(s_attn[tid * 32 + kk] - mx);
        s_hmax[tid] = mx;
        s_hsum[tid] = (sm > 0.0f) ? sm : 1.0f;
    }
    __syncthreads();
    if (tid < 128)
        s_attn[tid] = expf(s_attn[tid] - s_hmax[tid >> 5]) / s_hsum[tid >> 5];
    __syncthreads();

    if (mat == 1) {
#pragma unroll
        for (int kk = 0; kk < KMAX; ++kk) s_kv[kk][col] = acc[kk];
    }
    __syncthreads();

    if (tid < 128) {
        int h = tid >> 5, d = tid & 31;
        float o = 0.0f;
#pragma unroll
        for (int kk = 0; kk < KMAX; ++kk)
            o = fmaf(s_attn[h * 32 + kk], s_kv[kk][h * 32 + d], o);
        s_ao[d * 4 + h] = o;
    }
    __syncthreads();

    float upd = 0.0f;
    if (tid < 128) {
        upd = Pf[0 + tid];  // bo
#pragma unroll 4
        for (int i = 0; i < DIM; i += 4) {
            float4 a = *(const float4*)&s_ao[i];
            upd = fmaf(a.x, Wof[(i + 0) * DIM + tid], upd);
            upd = fmaf(a.y, Wof[(i + 1) * DIM + tid], upd);
            upd = fmaf(a.z, Wof[(i + 2) * DIM + tid], upd);
            upd = fmaf(a.w, Wof[(i + 3) * DIM + tid], upd);
        }
    }
    if (tid < 128) s_tree[tid] = upd;
    __syncthreads();
    for (int s = 64; s > 0; s >>= 1) { if (tid < s) s_tree[tid] += s_tree[tid + s]; __syncthreads(); }
    float mu = s_tree[0] * (1.0f / 128.0f);
    __syncthreads();
    float xc = upd - mu;
    if (tid < 128) s_tree[tid] = xc * xc;
    __syncthreads();
    for (int s = 64; s > 0; s >>= 1) { if (tid < s) s_tree[tid] += s_tree[tid + s]; __syncthreads(); }
    float var = s_tree[0] * (1.0f / 128.0f);
    __syncthreads();
    float cf1 = 0.0f;
    if (tid < 128) {
        float rs = 1.0f / sqrtf(var + LN_EPS);
        float ln1 = fmaf(xc * rs, Pf[128 + tid], Pf[256 + tid]);  // n1w, n1b
        cf1 = s_cf[tid] + ln1;
        s_x[tid] = cf1;
    }
    __syncthreads();

    float* s_h = (float*)&nft[0][0];
#pragma unroll
    for (int jj = 0; jj < 2; ++jj) {
        int j = jj * 256 + tid;
        float a = Pf[640 + j];  // b1
#pragma unroll 4
        for (int i = 0; i < DIM; i += 4) {
            float4 v = *(const float4*)&s_x[i];
            a = fmaf(v.x, W1f[(i + 0) * 512 + j], a);
            a = fmaf(v.y, W1f[(i + 1) * 512 + j], a);
            a = fmaf(v.z, W1f[(i + 2) * 512 + j], a);
            a = fmaf(v.w, W1f[(i + 3) * 512 + j], a);
        }
        s_h[j] = fmaxf(a, 0.0f);
    }
    __syncthreads();

    int half = tid >> 7;
    float f2 = (half == 0) ? Pf[1152 + col] : 0.0f;  // b2
    {
        int i0 = half * 256;
#pragma unroll 4
        for (int i = i0; i < i0 + 256; i += 4) {
            float4 v = *(const float4*)&s_h[i];
            f2 = fmaf(v.x, W2f[(i + 0) * DIM + col], f2);
            f2 = fmaf(v.y, W2f[(i + 1) * DIM + col], f2);
            f2 = fmaf(v.z, W2f[(i + 2) * DIM + col], f2);
            f2 = fmaf(v.w, W2f[(i + 3) * DIM + col], f2);
        }
    }
    s_part[tid] = f2;
    __syncthreads();
    float ffn = 0.0f;
    if (tid < 128) ffn = s_part[tid] + s_part[tid + 128];
    if (tid < 128) s_tree[tid] = ffn;
    __syncthreads();
    for (int s = 64; s > 0; s >>= 1) { if (tid < s) s_tree[tid] += s_tree[tid + s]; __syncthreads(); }
    mu = s_tree[0] * (1.0f / 128.0f);
    __syncthreads();
    xc = ffn - mu;
    if (tid < 128) s_tree[tid] = xc * xc;
    __syncthreads();
    for (int s = 64; s > 0; s >>= 1) { if (tid < s) s_tree[tid] += s_tree[tid + s]; __syncthreads(); }
    var = s_tree[0] * (1.0f / 128.0f);
    __syncthreads();
    if (tid < 128) {
        float rs2 = 1.0f / sqrtf(var + LN_EPS);
        float ln2 = fmaf(xc * rs2, Pf[384 + tid], Pf[512 + tid]);  // n2w, n2b
        cf_out[(size_t)m * DIM + tid] = cf1 + ln2;
    }
}

// =================== kernel: wave-per-point KNN + upsample + Wp + out ===================
// One wave per point; zero LDS, zero barriers; grid (N+3)/4 * 256thr -> ~49 blocks/CU.
// Lane l scans centers l, l+64, ... (per-lane top-8: set-exact, order-independent).
// Ascending merge: 8 rounds of 64-lane shfl-min (keys unique -> exact global top-8,
// ascending). All lanes track (d,idx) redundantly in registers; weights summed in
// ascending order; upsample k-ascending; GEMM i-ascending -> bit-identical output.
#define CSWAP(a, b) { if ((b) < (a)) { u64 t_ = (a); (a) = (b); (b) = t_; } }

__global__ __launch_bounds__(256) void knn_fused(
    const float4* __restrict__ pnt4,
    const float4* __restrict__ cent4,
    const float* __restrict__ cf,
    const float* __restrict__ Wf,
    const void* __restrict__ feats,
    const int* __restrict__ fl,
    float* __restrict__ out, int N, int M) {

    const float* Wpf = Wf + 196608;
    const float* bpf = Wf + 212992 + 1280;

    int lane = threadIdx.x & 63;
    int wv   = threadIdx.x >> 6;
    int p = blockIdx.x * 4 + wv;
    bool own = (p < N);
    int f1 = fl[1];

    float4 pp = make_float4(0.f, 0.f, 0.f, 0.f);
    if (own) pp = pnt4[p];          // own is wave-uniform

    // ---- per-lane top-8 over centers lane, lane+64, ... ----
    u64 b0 = ~0ULL, b1 = ~0ULL, b2 = ~0ULL, b3 = ~0ULL,
        b4 = ~0ULL, b5 = ~0ULL, b6 = ~0ULL, b7 = ~0ULL;
    for (int j = lane; j < M; j += 64) {
        float4 cc = cent4[j];
        float dist = dist32(cc.x, cc.y, cc.z, cc.w, pp.x, pp.y, pp.z, pp.w);
        u64 key = ((u64)__float_as_uint(dist) << 32) | (unsigned)j;
        if (key < b7) {
            b7 = key;
            CSWAP(b6, b7); CSWAP(b5, b6); CSWAP(b4, b5); CSWAP(b3, b4);
            CSWAP(b2, b3); CSWAP(b1, b2); CSWAP(b0, b1);
        }
    }

    // ---- 64-way ascending merge via shuffle-min; weights tracked by all lanes ----
    int   ptr = 0;
    u64   cur = b0;
    float wsum = 0.0f;
    int   ki[8];
    float w8[8];
#pragma unroll
    for (int e = 0; e < 8; ++e) {
        u64 v = cur;
        for (int off = 32; off; off >>= 1) {
            u64 o = __shfl_down(v, off, 64);
            v = (o < v) ? o : v;
        }
        u64 gm = __shfl(v, 0, 64);                 // global min, broadcast
        float d = __uint_as_float((unsigned)(gm >> 32));
        int ci = (int)(unsigned)(gm & 0xFFFFFFFFULL);
        ci = (ci >= 0 && ci < M) ? ci : 0;
        float t = __fadd_rn(d, 1e-6f);
        float w = 1.0f / __fmul_rn(t, t);
        wsum += w;                                 // ascending-order sum (bit-exact)
        ki[e] = ci;
        w8[e] = w;
        if (cur == gm) {                           // unique owner advances
            ptr++;
            cur = (ptr == 1) ? b1 : (ptr == 2) ? b2 : (ptr == 3) ? b3 :
                  (ptr == 4) ? b4 : (ptr == 5) ? b5 : (ptr == 6) ? b6 :
                  (ptr == 7) ? b7 : ~0ULL;
        }
    }
    float inv = 1.0f / wsum;
#pragma unroll
    for (int e = 0; e < 8; ++e) w8[e] *= inv;

    // ---- upsample: lane owns cols lane and lane+64 (k ascending, bit-exact) ----
    int c0 = lane, c1 = lane + 64;
    float up0 = 0.0f, up1 = 0.0f;
#pragma unroll
    for (int k = 0; k < 8; ++k) {
        const float* row = cf + (size_t)ki[k] * DIM;
        up0 = fmaf(w8[k], row[c0], up0);
        up1 = fmaf(w8[k], row[c1], up1);
    }

    // ---- Wp GEMM: i ascending via shuffle broadcast of up[i] ----
    float a0 = 0.0f, a1 = 0.0f;
    for (int i = 0; i < 64; ++i) {
        float u = __shfl(up0, i, 64);
        a0 = fmaf(u, Wpf[(size_t)i * DIM + c0], a0);
        a1 = fmaf(u, Wpf[(size_t)i * DIM + c1], a1);
    }
    for (int i = 0; i < 64; ++i) {
        float u = __shfl(up1, i, 64);
        a0 = fmaf(u, Wpf[(size_t)(64 + i) * DIM + c0], a0);
        a1 = fmaf(u, Wpf[(size_t)(64 + i) * DIM + c1], a1);
    }

    if (own) {
        float o0 = ldf(feats, f1, (size_t)p * DIM + c0) + up0 + fmaxf(bpf[c0] + a0, 0.0f);
        float o1 = ldf(feats, f1, (size_t)p * DIM + c1) + up1 + fmaxf(bpf[c1] + a1, 0.0f);
        out[(size_t)p * DIM + c0] = o0;
        out[(size_t)p * DIM + c1] = o1;
    }
}

extern "C" void kernel_launch(void* const* d_in, const int* in_sizes, int n_in,
                              void* d_out, int out_size, void* d_ws, size_t ws_size,
                              hipStream_t stream) {
    int N = in_sizes[0] / 3;
    int M = in_sizes[17];

    Ptrs P;
    for (int j = 0; j < 18; ++j) { P.p[j] = d_in[j]; P.sz[j] = in_sizes[j]; }

    size_t off = 0;
    auto alloc = [&](size_t bytes) -> void* {
        off = (off + 255) & ~(size_t)255;
        void* p = (void*)((char*)d_ws + off);
        off += bytes;
        return p;
    };
    int*    fl    = (int*)alloc(32 * 4);
    float*  Wf    = (float*)alloc((size_t)WTOT * 4);          // 858 KB
    float4* pnt4  = (float4*)alloc((size_t)N * 16);           // 800 KB
    float4* cent4 = (float4*)alloc((size_t)M * 16);           //  40 KB
    float*  cfbuf = (float*)alloc((size_t)M * DIM * 4);       // 1.28 MB
    int*    nbr   = (int*)alloc((size_t)M * KMAX * 4);        // 320 KB (total ~3.3 MB)

    probe_dtypes<<<1, 32, 0, stream>>>(P, fl);
    conv_params<<<(WTOT + 255) / 256, 256, 0, stream>>>(P, fl, Wf);
    prep_pts<<<(N + 255) / 256, 256, 0, stream>>>(d_in[0], fl, pnt4, N);
    prep_ctrs<<<(M + 255) / 256, 256, 0, stream>>>(d_in[17], fl, pnt4, cent4, M, N);
    ball_scan<<<M, 256, 0, stream>>>(pnt4, cent4, N, nbr);
    attn_ffn<<<M, 256, 0, stream>>>(nbr, d_in[1], d_in[17], fl, Wf, cfbuf, N);
    knn_fused<<<(N + 3) / 4, 256, 0, stream>>>(pnt4, cent4, cfbuf, Wf, d_in[1], fl,
                                               (float*)d_out, N, M);
}

// Round 17
// 635.933 us; speedup vs baseline: 2.0752x; 1.0748x over previous
//
#include <hip/hip_runtime.h>
#include <hip/hip_bf16.h>
#include <stdint.h>

#define DIM    128
#define KMAX   32
#define LN_EPS 1e-5f
#define ATT_SCALE 0.17677669529663687f   // 32^-0.5
#define CAND   2048
#define WTOT   214400                    // 212992 weight f32 + 1408 param f32

typedef unsigned long long u64;
static __device__ __forceinline__ float bf2f(__hip_bfloat16 x) { return __bfloat162float(x); }

// ---- bit-exact replica of the np-fp32 distance pipeline (DO NOT TOUCH: passing) ----
static __device__ __forceinline__ float norm32(float x, float y, float z) {
    return __fadd_rn(__fadd_rn(__fmul_rn(x, x), __fmul_rn(y, y)), __fmul_rn(z, z));
}
static __device__ __forceinline__ float d2_32(float cx, float cy, float cz, float cw,
                                              float px, float py, float pz, float pw) {
    float dot = __fmaf_rn(cz, pz, __fmaf_rn(cy, py, __fmul_rn(cx, px)));
    return __fsub_rn(__fadd_rn(cw, pw), __fmul_rn(2.0f, dot));
}
static __device__ __forceinline__ float d2_to_dist(float d2) {
    d2 = fmaxf(d2, 0.0f);
    return (d2 > 0.0f) ? __fsqrt_rn(d2) : 0.0f;
}
static __device__ __forceinline__ float dist32(float cx, float cy, float cz, float cw,
                                               float px, float py, float pz, float pw) {
    return d2_to_dist(d2_32(cx, cy, cz, cw, px, py, pz, pw));
}

static __device__ __forceinline__ float ldf(const void* p, int f32, size_t i) {
    return f32 ? ((const float*)p)[i] : bf2f(((const __hip_bfloat16*)p)[i]);
}
static __device__ __forceinline__ int ldidx(const void* p, int i64, int m) {
    return i64 ? ((const int*)p)[2 * m] : ((const int*)p)[m];
}

struct Ptrs { const void* p[18]; int sz[18]; };

// ---------- probe: classify each input's dtype on-device (unchanged, passing) ----------
__global__ void probe_dtypes(Ptrs P, int* __restrict__ fl) {
    int j = threadIdx.x;
    if (j >= 18) return;
    const void* x = P.p[j];
    int sz = P.sz[j];
    int flag = 0;
    if (j == 17) {
        const int* ip = (const int*)x;
        int odd_zero = 1, even_nz = 0;
        for (int k = 0; k < 8 && 2 * k + 1 < sz * 2; ++k) {
            if (ip[2 * k + 1] != 0) odd_zero = 0;
            if (ip[2 * k] != 0) even_nz = 1;
        }
        flag = (odd_zero && even_nz) ? 1 : 0;
    } else {
        const __hip_bfloat16* hp = (const __hip_bfloat16*)x;
        int n = sz < 256 ? sz : 256;
        for (int i = 0; i < n; ++i) {
            float w = bf2f(hp[i]);
            if (w != w || fabsf(w) > 1000.0f) { flag = 1; break; }
        }
        if ((j == 7 || j == 9) && bf2f(hp[0]) == 0.0f) flag = 1;
    }
    fl[j] = flag;
}

// ---------- convert weights+params -> canonical fp32 (unchanged) ----------
__global__ __launch_bounds__(256) void conv_params(Ptrs P, const int* __restrict__ fl,
                                                   float* __restrict__ Wf) {
    int i = blockIdx.x * 256 + threadIdx.x;
    if (i >= WTOT) return;
    int j, off;
    if      (i < 16384)  { j = 2;  off = i; }
    else if (i < 32768)  { j = 3;  off = i - 16384; }
    else if (i < 49152)  { j = 4;  off = i - 32768; }
    else if (i < 65536)  { j = 5;  off = i - 49152; }
    else if (i < 131072) { j = 11; off = i - 65536; }
    else if (i < 196608) { j = 13; off = i - 131072; }
    else if (i < 212992) { j = 15; off = i - 196608; }
    else if (i < 213120) { j = 6;  off = i - 212992; }
    else if (i < 213248) { j = 7;  off = i - 213120; }
    else if (i < 213376) { j = 8;  off = i - 213248; }
    else if (i < 213504) { j = 9;  off = i - 213376; }
    else if (i < 213632) { j = 10; off = i - 213504; }
    else if (i < 214144) { j = 12; off = i - 213632; }
    else if (i < 214272) { j = 14; off = i - 214144; }
    else                 { j = 16; off = i - 214272; }
    Wf[i] = ldf(P.p[j], fl[j], off);
}

__global__ void prep_pts(const void* __restrict__ xyz, const int* __restrict__ fl,
                         float4* __restrict__ pnt4, int N) {
    int i = blockIdx.x * 256 + threadIdx.x;
    if (i < N) {
        int f = fl[0];
        float x = ldf(xyz, f, 3 * i + 0), y = ldf(xyz, f, 3 * i + 1), z = ldf(xyz, f, 3 * i + 2);
        pnt4[i] = make_float4(x, y, z, norm32(x, y, z));
    }
}

__global__ void prep_ctrs(const void* __restrict__ idxc, const int* __restrict__ fl,
                          const float4* __restrict__ pnt4, float4* __restrict__ cent4,
                          int M, int N) {
    int m = blockIdx.x * 256 + threadIdx.x;
    if (m < M) {
        int c = ldidx(idxc, fl[17], m);
        c = (c >= 0 && c < N) ? c : 0;
        cent4[m] = pnt4[c];
    }
}

// =================== kernel: ball query scan + top-32 select -> nbr_g (unchanged) ===================
__global__ __launch_bounds__(256) void ball_scan(
    const float4* __restrict__ pnt4,
    const float4* __restrict__ cent4,
    int N, int* __restrict__ nbr_g) {

    __shared__ u64 key[CAND];        // 16 KB
    __shared__ int s_cnt, s_ni[KMAX];

    int m = blockIdx.x, tid = threadIdx.x;
    float4 cc4 = cent4[m];

    if (tid == 0) s_cnt = 0;
    if (tid < KMAX) s_ni[tid] = -1;
    __syncthreads();

    for (int i = tid; i < N; i += 256) {
        float4 p = pnt4[i];
        float d2 = d2_32(cc4.x, cc4.y, cc4.z, cc4.w, p.x, p.y, p.z, p.w);
        if (d2 < 0.0901f) {
            float dist = d2_to_dist(d2);
            if (dist < 0.3f) {
                int pos = atomicAdd(&s_cnt, 1);
                if (pos < CAND)
                    key[pos] = ((u64)__float_as_uint(dist) << 32) | (unsigned)i;
            }
        }
    }
    __syncthreads();
    int cnt = min(s_cnt, CAND);

    for (int i = tid; i < cnt; i += 256) {
        u64 ki = key[i];
        int r = 0;
        for (int j = 0; j < cnt; ++j) r += (key[j] < ki) ? 1 : 0;
        if (r < KMAX) s_ni[r] = (int)(unsigned)(ki & 0xFFFFFFFFULL);
    }
    __syncthreads();
    if (tid < KMAX) nbr_g[m * KMAX + tid] = s_ni[tid];
}

// =================== kernel: attention + FFN -> cf (unchanged, passing) ===================
__global__ __launch_bounds__(256) void attn_ffn(
    const int* __restrict__ nbr_g,
    const void* __restrict__ feats,
    const void* __restrict__ idxc,
    const int* __restrict__ fl,
    const float* __restrict__ Wf,
    float* __restrict__ cf_out, int N) {

    const float* Wqf = Wf;
    const float* Wkf = Wf + 16384;
    const float* Wvf = Wf + 32768;
    const float* Wof = Wf + 49152;
    const float* W1f = Wf + 65536;
    const float* W2f = Wf + 131072;
    const float* Pf  = Wf + 212992;

    __shared__ __align__(16) float nft[DIM][33];
    __shared__ float s_kv[KMAX][130];
    __shared__ int   s_ni[KMAX];
    __shared__ __align__(16) float s_cf[DIM], s_q[DIM], s_attn[DIM], s_ao[DIM], s_x[DIM];
    __shared__ float s_tree[128], s_part[256];
    __shared__ float s_hmax[4], s_hsum[4];

    int m = blockIdx.x, tid = threadIdx.x;
    int f1 = fl[1];
    int c = ldidx(idxc, fl[17], m);
    c = (c >= 0 && c < N) ? c : 0;

    if (tid < KMAX) s_ni[tid] = nbr_g[m * KMAX + tid];
    if (tid < 128) s_cf[tid] = ldf(feats, f1, (size_t)c * DIM + tid);
    __syncthreads();
    for (int t = tid; t < KMAX * DIM; t += 256) {
        int kk = t >> 7, cc = t & 127;
        int idx = s_ni[kk];
        float v = (idx >= 0 && idx < N) ? ldf(feats, f1, (size_t)idx * DIM + cc) : 0.0f;
        nft[cc][kk] = v;
    }
    __syncthreads();

    if (tid < 128) {
        float acc = 0.0f;
#pragma unroll 4
        for (int i = 0; i < DIM; i += 4) {
            float4 a = *(const float4*)&s_cf[i];
            acc = fmaf(a.x, Wqf[(i + 0) * DIM + tid], acc);
            acc = fmaf(a.y, Wqf[(i + 1) * DIM + tid], acc);
            acc = fmaf(a.z, Wqf[(i + 2) * DIM + tid], acc);
            acc = fmaf(a.w, Wqf[(i + 3) * DIM + tid], acc);
        }
        s_q[tid] = acc;
    }

    int mat = tid >> 7, col = tid & 127;
    const float* Wm = mat ? Wvf : Wkf;
    float acc[KMAX];
#pragma unroll
    for (int kk = 0; kk < KMAX; ++kk) acc[kk] = 0.0f;
    for (int i = 0; i < DIM; ++i) {
        float w = Wm[i * DIM + col];
#pragma unroll
        for (int k4 = 0; k4 < 8; ++k4) {
            float4 n = *(const float4*)&nft[i][k4 * 4];
            acc[k4 * 4 + 0] = fmaf(n.x, w, acc[k4 * 4 + 0]);
            acc[k4 * 4 + 1] = fmaf(n.y, w, acc[k4 * 4 + 1]);
            acc[k4 * 4 + 2] = fmaf(n.z, w, acc[k4 * 4 + 2]);
            acc[k4 * 4 + 3] = fmaf(n.w, w, acc[k4 * 4 + 3]);
        }
    }
    if (mat == 0) {
#pragma unroll
        for (int kk = 0; kk < KMAX; ++kk) s_kv[kk][col] = acc[kk];
    }
    __syncthreads();

    if (tid < 128) {
        int h = tid >> 5, kk = tid & 31;
        float s = 0.0f;
#pragma unroll
        for (int d = 0; d < 32; ++d)
            s = fmaf(s_q[h * 32 + d], s_kv[kk][h * 32 + d], s);
        s *= ATT_SCALE;
        if (s_ni[kk] < 0) s = -1e9f;
        s_attn[tid] = s;
    }
    __syncthreads();
    if (tid < 4) {
        float mx = -3.4e38f;
        for (int kk = 0; kk < 32; ++kk) mx = fmaxf(mx, s_attn[tid * 32 + kk]);
        float sm = 0.0f;
        for (int kk = 0; kk < 32; ++kk) sm += expf(s_attn[tid * 32 + kk] - mx);
        s_hmax[tid] = mx;
        s_hsum[tid] = (sm > 0.0f) ? sm : 1.0f;
    }
    __syncthreads();
    if (tid < 128)
        s_attn[tid] = expf(s_attn[tid] - s_hmax[tid >> 5]) / s_hsum[tid >> 5];
    __syncthreads();

    if (mat == 1) {
#pragma unroll
        for (int kk = 0; kk < KMAX; ++kk) s_kv[kk][col] = acc[kk];
    }
    __syncthreads();

    if (tid < 128) {
        int h = tid >> 5, d = tid & 31;
        float o = 0.0f;
#pragma unroll
        for (int kk = 0; kk < KMAX; ++kk)
            o = fmaf(s_attn[h * 32 + kk], s_kv[kk][h * 32 + d], o);
        s_ao[d * 4 + h] = o;
    }
    __syncthreads();

    float upd = 0.0f;
    if (tid < 128) {
        upd = Pf[0 + tid];  // bo
#pragma unroll 4
        for (int i = 0; i < DIM; i += 4) {
            float4 a = *(const float4*)&s_ao[i];
            upd = fmaf(a.x, Wof[(i + 0) * DIM + tid], upd);
            upd = fmaf(a.y, Wof[(i + 1) * DIM + tid], upd);
            upd = fmaf(a.z, Wof[(i + 2) * DIM + tid], upd);
            upd = fmaf(a.w, Wof[(i + 3) * DIM + tid], upd);
        }
    }
    if (tid < 128) s_tree[tid] = upd;
    __syncthreads();
    for (int s = 64; s > 0; s >>= 1) { if (tid < s) s_tree[tid] += s_tree[tid + s]; __syncthreads(); }
    float mu = s_tree[0] * (1.0f / 128.0f);
    __syncthreads();
    float xc = upd - mu;
    if (tid < 128) s_tree[tid] = xc * xc;
    __syncthreads();
    for (int s = 64; s > 0; s >>= 1) { if (tid < s) s_tree[tid] += s_tree[tid + s]; __syncthreads(); }
    float var = s_tree[0] * (1.0f / 128.0f);
    __syncthreads();
    float cf1 = 0.0f;
    if (tid < 128) {
        float rs = 1.0f / sqrtf(var + LN_EPS);
        float ln1 = fmaf(xc * rs, Pf[128 + tid], Pf[256 + tid]);  // n1w, n1b
        cf1 = s_cf[tid] + ln1;
        s_x[tid] = cf1;
    }
    __syncthreads();

    float* s_h = (float*)&nft[0][0];
#pragma unroll
    for (int jj = 0; jj < 2; ++jj) {
        int j = jj * 256 + tid;
        float a = Pf[640 + j];  // b1
#pragma unroll 4
        for (int i = 0; i < DIM; i += 4) {
            float4 v = *(const float4*)&s_x[i];
            a = fmaf(v.x, W1f[(i + 0) * 512 + j], a);
            a = fmaf(v.y, W1f[(i + 1) * 512 + j], a);
            a = fmaf(v.z, W1f[(i + 2) * 512 + j], a);
            a = fmaf(v.w, W1f[(i + 3) * 512 + j], a);
        }
        s_h[j] = fmaxf(a, 0.0f);
    }
    __syncthreads();

    int half = tid >> 7;
    float f2 = (half == 0) ? Pf[1152 + col] : 0.0f;  // b2
    {
        int i0 = half * 256;
#pragma unroll 4
        for (int i = i0; i < i0 + 256; i += 4) {
            float4 v = *(const float4*)&s_h[i];
            f2 = fmaf(v.x, W2f[(i + 0) * DIM + col], f2);
            f2 = fmaf(v.y, W2f[(i + 1) * DIM + col], f2);
            f2 = fmaf(v.z, W2f[(i + 2) * DIM + col], f2);
            f2 = fmaf(v.w, W2f[(i + 3) * DIM + col], f2);
        }
    }
    s_part[tid] = f2;
    __syncthreads();
    float ffn = 0.0f;
    if (tid < 128) ffn = s_part[tid] + s_part[tid + 128];
    if (tid < 128) s_tree[tid] = ffn;
    __syncthreads();
    for (int s = 64; s > 0; s >>= 1) { if (tid < s) s_tree[tid] += s_tree[tid + s]; __syncthreads(); }
    mu = s_tree[0] * (1.0f / 128.0f);
    __syncthreads();
    xc = ffn - mu;
    if (tid < 128) s_tree[tid] = xc * xc;
    __syncthreads();
    for (int s = 64; s > 0; s >>= 1) { if (tid < s) s_tree[tid] += s_tree[tid + s]; __syncthreads(); }
    var = s_tree[0] * (1.0f / 128.0f);
    __syncthreads();
    if (tid < 128) {
        float rs2 = 1.0f / sqrtf(var + LN_EPS);
        float ln2 = fmaf(xc * rs2, Pf[384 + tid], Pf[512 + tid]);  // n2w, n2b
        cf_out[(size_t)m * DIM + tid] = cf1 + ln2;
    }
}

// =================== kernel: wave-per-point KNN + upsample + Wp + out ===================
// Fast path: per-lane top-3 chain (insert ~11 ops vs ~35 for 8-deep). Exact unless some
// lane contributes >=3 of the global top-8 (prob ~1.3%/wave) -> detected via ballot(ptr>=3),
// wave falls back to the full 8-deep scan+merge (the R16-proven code). Weight order,
// upsample, GEMM unchanged -> bit-identical output.
#define CSWAP(a, b) { if ((b) < (a)) { u64 t_ = (a); (a) = (b); (b) = t_; } }

__global__ __launch_bounds__(256) void knn_fused(
    const float4* __restrict__ pnt4,
    const float4* __restrict__ cent4,
    const float* __restrict__ cf,
    const float* __restrict__ Wf,
    const void* __restrict__ feats,
    const int* __restrict__ fl,
    float* __restrict__ out, int N, int M) {

    const float* Wpf = Wf + 196608;
    const float* bpf = Wf + 212992 + 1280;

    int lane = threadIdx.x & 63;
    int wv   = threadIdx.x >> 6;
    int p = blockIdx.x * 4 + wv;
    bool own = (p < N);
    int f1 = fl[1];

    float4 pp = make_float4(0.f, 0.f, 0.f, 0.f);
    if (own) pp = pnt4[p];          // own is wave-uniform

    // ---- fast scan: per-lane top-3 ----
    u64 b0 = ~0ULL, b1 = ~0ULL, b2 = ~0ULL;
    for (int j = lane; j < M; j += 64) {
        float4 cc = cent4[j];
        float dist = dist32(cc.x, cc.y, cc.z, cc.w, pp.x, pp.y, pp.z, pp.w);
        u64 key = ((u64)__float_as_uint(dist) << 32) | (unsigned)j;
        if (key < b2) {
            b2 = key;
            CSWAP(b1, b2); CSWAP(b0, b1);
        }
    }

    // ---- ascending merge from top-3 heads ----
    int   ptr = 0;
    u64   cur = b0;
    float wsum = 0.0f;
    int   ki[8];
    float w8[8];
#pragma unroll
    for (int e = 0; e < 8; ++e) {
        u64 v = cur;
        for (int off = 32; off; off >>= 1) {
            u64 o = __shfl_down(v, off, 64);
            v = (o < v) ? o : v;
        }
        u64 gm = __shfl(v, 0, 64);                 // global min, broadcast
        float d = __uint_as_float((unsigned)(gm >> 32));
        int ci = (int)(unsigned)(gm & 0xFFFFFFFFULL);
        ci = (ci >= 0 && ci < M) ? ci : 0;
        float t = __fadd_rn(d, 1e-6f);
        float w = 1.0f / __fmul_rn(t, t);
        wsum += w;                                 // ascending-order sum (bit-exact)
        ki[e] = ci;
        w8[e] = w;
        if (cur == gm) {                           // unique owner advances
            ptr++;
            cur = (ptr == 1) ? b1 : (ptr == 2) ? b2 : ~0ULL;
        }
    }

    // ---- exactness check: any lane exhausted its 3 -> full 8-deep rescan ----
    if (__ballot(ptr >= 3) != 0ULL) {
        u64 f0 = ~0ULL, f1_ = ~0ULL, f2_ = ~0ULL, f3 = ~0ULL,
            f4 = ~0ULL, f5 = ~0ULL, f6 = ~0ULL, f7 = ~0ULL;
        for (int j = lane; j < M; j += 64) {
            float4 cc = cent4[j];
            float dist = dist32(cc.x, cc.y, cc.z, cc.w, pp.x, pp.y, pp.z, pp.w);
            u64 key = ((u64)__float_as_uint(dist) << 32) | (unsigned)j;
            if (key < f7) {
                f7 = key;
                CSWAP(f6, f7); CSWAP(f5, f6); CSWAP(f4, f5); CSWAP(f3, f4);
                CSWAP(f2_, f3); CSWAP(f1_, f2_); CSWAP(f0, f1_);
            }
        }
        int ptr2 = 0;
        u64 cur2 = f0;
        wsum = 0.0f;
#pragma unroll
        for (int e = 0; e < 8; ++e) {
            u64 v = cur2;
            for (int off = 32; off; off >>= 1) {
                u64 o = __shfl_down(v, off, 64);
                v = (o < v) ? o : v;
            }
            u64 gm = __shfl(v, 0, 64);
            float d = __uint_as_float((unsigned)(gm >> 32));
            int ci = (int)(unsigned)(gm & 0xFFFFFFFFULL);
            ci = (ci >= 0 && ci < M) ? ci : 0;
            float t = __fadd_rn(d, 1e-6f);
            float w = 1.0f / __fmul_rn(t, t);
            wsum += w;
            ki[e] = ci;
            w8[e] = w;
            if (cur2 == gm) {
                ptr2++;
                cur2 = (ptr2 == 1) ? f1_ : (ptr2 == 2) ? f2_ : (ptr2 == 3) ? f3 :
                       (ptr2 == 4) ? f4 : (ptr2 == 5) ? f5 : (ptr2 == 6) ? f6 :
                       (ptr2 == 7) ? f7 : ~0ULL;
            }
        }
    }

    float inv = 1.0f / wsum;
#pragma unroll
    for (int e = 0; e < 8; ++e) w8[e] *= inv;

    // ---- upsample: lane owns cols lane and lane+64 (k ascending, bit-exact) ----
    int c0 = lane, c1 = lane + 64;
    float up0 = 0.0f, up1 = 0.0f;
#pragma unroll
    for (int k = 0; k < 8; ++k) {
        const float* row = cf + (size_t)ki[k] * DIM;
        up0 = fmaf(w8[k], row[c0], up0);
        up1 = fmaf(w8[k], row[c1], up1);
    }

    // ---- Wp GEMM: i ascending via shuffle broadcast of up[i] ----
    float a0 = 0.0f, a1 = 0.0f;
    for (int i = 0; i < 64; ++i) {
        float u = __shfl(up0, i, 64);
        a0 = fmaf(u, Wpf[(size_t)i * DIM + c0], a0);
        a1 = fmaf(u, Wpf[(size_t)i * DIM + c1], a1);
    }
    for (int i = 0; i < 64; ++i) {
        float u = __shfl(up1, i, 64);
        a0 = fmaf(u, Wpf[(size_t)(64 + i) * DIM + c0], a0);
        a1 = fmaf(u, Wpf[(size_t)(64 + i) * DIM + c1], a1);
    }

    if (own) {
        float o0 = ldf(feats, f1, (size_t)p * DIM + c0) + up0 + fmaxf(bpf[c0] + a0, 0.0f);
        float o1 = ldf(feats, f1, (size_t)p * DIM + c1) + up1 + fmaxf(bpf[c1] + a1, 0.0f);
        out[(size_t)p * DIM + c0] = o0;
        out[(size_t)p * DIM + c1] = o1;
    }
}

extern "C" void kernel_launch(void* const* d_in, const int* in_sizes, int n_in,
                              void* d_out, int out_size, void* d_ws, size_t ws_size,
                              hipStream_t stream) {
    int N = in_sizes[0] / 3;
    int M = in_sizes[17];

    Ptrs P;
    for (int j = 0; j < 18; ++j) { P.p[j] = d_in[j]; P.sz[j] = in_sizes[j]; }

    size_t off = 0;
    auto alloc = [&](size_t bytes) -> void* {
        off = (off + 255) & ~(size_t)255;
        void* p = (void*)((char*)d_ws + off);
        off += bytes;
        return p;
    };
    int*    fl    = (int*)alloc(32 * 4);
    float*  Wf    = (float*)alloc((size_t)WTOT * 4);          // 858 KB
    float4* pnt4  = (float4*)alloc((size_t)N * 16);           // 800 KB
    float4* cent4 = (float4*)alloc((size_t)M * 16);           //  40 KB
    float*  cfbuf = (float*)alloc((size_t)M * DIM * 4);       // 1.28 MB
    int*    nbr   = (int*)alloc((size_t)M * KMAX * 4);        // 320 KB (total ~3.3 MB)

    probe_dtypes<<<1, 32, 0, stream>>>(P, fl);
    conv_params<<<(WTOT + 255) / 256, 256, 0, stream>>>(P, fl, Wf);
    prep_pts<<<(N + 255) / 256, 256, 0, stream>>>(d_in[0], fl, pnt4, N);
    prep_ctrs<<<(M + 255) / 256, 256, 0, stream>>>(d_in[17], fl, pnt4, cent4, M, N);
    ball_scan<<<M, 256, 0, stream>>>(pnt4, cent4, N, nbr);
    attn_ffn<<<M, 256, 0, stream>>>(nbr, d_in[1], d_in[17], fl, Wf, cfbuf, N);
    knn_fused<<<(N + 3) / 4, 256, 0, stream>>>(pnt4, cent4, cfbuf, Wf, d_in[1], fl,
                                               (float*)d_out, N, M);
}